// Round 3
// baseline (363.989 us; speedup 1.0000x reference)
//
#include <hip/hip_runtime.h>
#include <hip/hip_bf16.h>

// GIN: 3x fused [CSR gather-sum + MLP(64->64->64) + relu] + mean-pool(128) + linear(64->10)
// gmlp v3: 512-thread blocks (8 waves), 64 rows/block. Each wave gathers 8 rows as
//   2 iterations x 4 concurrent streams (quad 8-deep load pipelines, ~32 loads in
//   flight at peak). Gather is latency-bound: BW ~ waves x depth (r1/r2 A/B).
//   __launch_bounds__(512,8) pins VGPR<=64 so the 32-wave/CU cap survives.
//   Wave PAIRS share a 16-row MFMA tile (each wave 2 of 4 col-tiles).
// CSR: 391-bucket binning + per-bucket counting sort w/ inline prefix.
// tobf zeroes bcnt+gsum. 7 dispatches total.

#define N_NODES 100000
#define N_EDGES 1200000
#define N_GRAPH 128
#define N_CLS   10
#define NBUCK   391        // dst >> 8
#define BCAP    4096       // per-bucket capacity (mean 3070, +18 sigma)
#define BSH     12         // log2(BCAP)

typedef __bf16 bf16_t;
typedef __bf16 bf16x8 __attribute__((ext_vector_type(8)));
typedef float  f32x4  __attribute__((ext_vector_type(4)));

// ---------------- x -> bf16 (+ zero bcnt/gsum for later kernels) ----------------
__global__ void tobf_kernel(const float* __restrict__ x, bf16_t* __restrict__ xb,
                            int* __restrict__ bcnt, float* __restrict__ gsum) {
    if (blockIdx.x == 0) {
        for (int i = threadIdx.x; i < NBUCK; i += 256) bcnt[i] = 0;
    } else if (blockIdx.x == 1) {
        f32x4* g4 = (f32x4*)gsum;
        for (int i = threadIdx.x; i < N_GRAPH * 16; i += 256)   // 8192 f32
            g4[i] = (f32x4){0.f, 0.f, 0.f, 0.f};
    }
    const int i = (blockIdx.x * 256 + threadIdx.x) * 8;
    const f32x4 a = *(const f32x4*)(x + i);
    const f32x4 b = *(const f32x4*)(x + i + 4);
    bf16x8 o;
#pragma unroll
    for (int j = 0; j < 4; ++j) { o[j] = (bf16_t)a[j]; o[4 + j] = (bf16_t)b[j]; }
    *(bf16x8*)(xb + i) = o;
}

// ---------------- CSR build ----------------
__global__ void binA_kernel(const int* __restrict__ ei,
                            int* __restrict__ bcnt,
                            int* __restrict__ bpair) {
    __shared__ int lcnt[NBUCK];
    __shared__ int lbase[NBUCK];
    const int t = threadIdx.x;
    for (int b = t; b < NBUCK; b += 256) lcnt[b] = 0;
    __syncthreads();
    const int e0 = (blockIdx.x * 256 + t) * 4;
    int4 s4, d4; int b[4], r[4];
    const bool valid = e0 < N_EDGES;               // N_EDGES % 4 == 0
    if (valid) {
        s4 = *(const int4*)(ei + e0);
        d4 = *(const int4*)(ei + N_EDGES + e0);
        b[0] = d4.x >> 8; b[1] = d4.y >> 8; b[2] = d4.z >> 8; b[3] = d4.w >> 8;
        r[0] = atomicAdd(&lcnt[b[0]], 1);
        r[1] = atomicAdd(&lcnt[b[1]], 1);
        r[2] = atomicAdd(&lcnt[b[2]], 1);
        r[3] = atomicAdd(&lcnt[b[3]], 1);
    }
    __syncthreads();
    for (int bb = t; bb < NBUCK; bb += 256) {
        const int c = lcnt[bb];
        lbase[bb] = c ? atomicAdd(&bcnt[bb], c) : 0;
    }
    __syncthreads();
    if (valid) {
        const int ss[4] = {s4.x, s4.y, s4.z, s4.w};
        const int dd[4] = {d4.x, d4.y, d4.z, d4.w};
#pragma unroll
        for (int j = 0; j < 4; ++j) {
            const int slot = lbase[b[j]] + r[j];
            if (slot < BCAP)
                bpair[(b[j] << BSH) + slot] = (ss[j] << 8) | (dd[j] & 255);
        }
    }
}

// one WG per bucket: inline prefix over min(bcnt,BCAP) + LDS counting sort
__global__ void sortfill_kernel(const int* __restrict__ bpair,
                                const int* __restrict__ bcnt,
                                int* __restrict__ offset, int* __restrict__ csr) {
    __shared__ int red[256];
    __shared__ int hist[256];
    __shared__ int l[256];
    __shared__ int cursor[256];
    const int b = blockIdx.x;
    const int t = threadIdx.x;
    const int base = b << BSH;

    // prefix: cbase = sum_{i<b} min(bcnt[i],BCAP); cnt = min(bcnt[b],BCAP)
    int part = 0;
    for (int i = t; i < b; i += 256) {
        int c = bcnt[i];
        part += (c < BCAP ? c : BCAP);
    }
    red[t] = part;
    __syncthreads();
    for (int d = 128; d > 0; d >>= 1) {
        if (t < d) red[t] += red[t + d];
        __syncthreads();
    }
    const int cbase = red[0];
    int cnt = bcnt[b];
    cnt = cnt < BCAP ? cnt : BCAP;
    if (b == NBUCK - 1 && t == 0) offset[N_NODES] = cbase + cnt;
    __syncthreads();

    hist[t] = 0;
    __syncthreads();
    for (int i = t; i < cnt; i += 256)
        atomicAdd(&hist[bpair[base + i] & 255], 1);
    __syncthreads();

    const int v = hist[t];
    l[t] = v;
    __syncthreads();
    for (int d = 1; d < 256; d <<= 1) {
        int u = l[t];
        if (t >= d) u += l[t - d];
        __syncthreads();
        l[t] = u;
        __syncthreads();
    }
    const int gpos = cbase + l[t] - v;              // exclusive
    const int node = (b << 8) + t;
    if (node < N_NODES) offset[node] = gpos;
    cursor[t] = gpos;
    __syncthreads();

    for (int i = t; i < cnt; i += 256) {
        const int p = bpair[base + i];
        const int pos = atomicAdd(&cursor[p & 255], 1);
        csr[pos] = p >> 8;
    }
}

// ---------------------------------------------------------------------------
// Gather macros: independent 8-deep / 4-deep load pipelines.
// ---------------------------------------------------------------------------
#define GATHER8(S, J, ACC)                                                     \
    {                                                                          \
        const int t0 = __shfl(S, J + 0), t1 = __shfl(S, J + 1);                \
        const int t2 = __shfl(S, J + 2), t3 = __shfl(S, J + 3);                \
        const int t4 = __shfl(S, J + 4), t5 = __shfl(S, J + 5);                \
        const int t6 = __shfl(S, J + 6), t7 = __shfl(S, J + 7);                \
        const float u0 = (float)x[t0 * 64 + f], u1 = (float)x[t1 * 64 + f];    \
        const float u2 = (float)x[t2 * 64 + f], u3 = (float)x[t3 * 64 + f];    \
        const float u4 = (float)x[t4 * 64 + f], u5 = (float)x[t5 * 64 + f];    \
        const float u6 = (float)x[t6 * 64 + f], u7 = (float)x[t7 * 64 + f];    \
        ACC += ((u0 + u1) + (u2 + u3)) + ((u4 + u5) + (u6 + u7));              \
    }
#define GATHER4(S, J, ACC)                                                     \
    {                                                                          \
        const int t0 = __shfl(S, J + 0), t1 = __shfl(S, J + 1);                \
        const int t2 = __shfl(S, J + 2), t3 = __shfl(S, J + 3);                \
        const float u0 = (float)x[t0 * 64 + f], u1 = (float)x[t1 * 64 + f];    \
        const float u2 = (float)x[t2 * 64 + f], u3 = (float)x[t3 * 64 + f];    \
        ACC += (u0 + u1) + (u2 + u3);                                          \
    }
// per-stream tail: 8-deep chunks, then 4, then scalars
#define TAIL(S, JJ, CNT, ACC)                                                  \
    for (; JJ + 8 <= CNT; JJ += 8) { GATHER8(S, JJ, ACC) }                     \
    if (JJ + 4 <= CNT) { GATHER4(S, JJ, ACC) JJ += 4; }                        \
    for (; JJ < CNT; ++JJ) {                                                   \
        const int tt = __shfl(S, JJ);                                          \
        ACC += (float)x[tt * 64 + f];                                          \
    }

// ---------------------------------------------------------------------------
// Fused gather + MLP, wave-paired, quad-stream gather.
// Block = 512 threads = 8 waves = 4 pairs; block covers 64 rows (4 x 16-row tiles).
// Wave w: pair p=w>>1, half=w&1. Gathers 8 rows (local rows half*8 .. half*8+7)
// as 2 iterations x 4 streams into hs[p]; pair computes 16x64 MLP,
// each wave owning 2 of 4 col-tiles.
// POOL=1 (layer 3): half==0 wave does segmented mean-pool numerator atomics.
// ---------------------------------------------------------------------------
template <int POOL>
__global__ __launch_bounds__(512, 8)
void gmlp_kernel(const bf16_t* __restrict__ x,
                 const int* __restrict__ offset,
                 const int* __restrict__ csr,
                 const float* __restrict__ wa, const float* __restrict__ ba,
                 const float* __restrict__ wb, const float* __restrict__ bb,
                 bf16_t* __restrict__ xout,
                 const int* __restrict__ batch,
                 float* __restrict__ gsum) {
    __shared__ __align__(16) bf16_t wfrag[2][8][64][8];  // [mat][ct*2+ks][lane][j]
    __shared__ __align__(16) bf16_t hs[4][16][72];       // per-pair: agg rows, then h2
    __shared__ __align__(16) bf16_t h2[4][16][72];       // per-pair: h1 (GEMM1 out)
    __shared__ float biasA[64], biasB[64];

    const int tid  = threadIdx.x;
    const int wv   = tid >> 6;          // 0..7
    const int p    = wv >> 1;           // pair 0..3
    const int half = wv & 1;
    const int lane = tid & 63;
    const int l15  = lane & 15;
    const int quad = lane >> 4;

    if (tid < 256) {
        const int k  = tid >> 2;
        const int n0 = (tid & 3) << 4;
        const int ks = k >> 5, qd = (k >> 3) & 3, jj = k & 7;
        const int fi = ((n0 >> 4) << 1) + ks;
#pragma unroll
        for (int m = 0; m < 2; ++m) {
            const float* w = m ? wb : wa;
            const f32x4 v0 = *(const f32x4*)(w + k * 64 + n0);
            const f32x4 v1 = *(const f32x4*)(w + k * 64 + n0 + 4);
            const f32x4 v2 = *(const f32x4*)(w + k * 64 + n0 + 8);
            const f32x4 v3 = *(const f32x4*)(w + k * 64 + n0 + 12);
#pragma unroll
            for (int l = 0; l < 4; ++l) {
                wfrag[m][fi][qd * 16 + l][jj]      = (bf16_t)v0[l];
                wfrag[m][fi][qd * 16 + 4 + l][jj]  = (bf16_t)v1[l];
                wfrag[m][fi][qd * 16 + 8 + l][jj]  = (bf16_t)v2[l];
                wfrag[m][fi][qd * 16 + 12 + l][jj] = (bf16_t)v3[l];
            }
        }
        if (tid < 64) biasA[tid] = ba[tid];
        else if (tid < 128) biasB[tid - 64] = bb[tid - 64];
    }
    // no sync here: the sync after the gather phase makes wfrag/bias visible.

    const int rbp = blockIdx.x * 64 + p * 16;   // pair's first row
    const int r0w = rbp + half * 8;             // this wave's first row
    const int f   = lane;

    // prefetch the 9 offsets this wave needs (rows r0w..r0w+8), broadcast via shfl
    int offv = 0;
    {
        int rr = r0w + lane;
        rr = rr < N_NODES ? rr : N_NODES;
        if (lane < 9) offv = offset[rr];
    }

    // ---- gather 8 rows into hs[p]: 2 iterations x 4 concurrent streams ----
#pragma unroll
    for (int it = 0; it < 2; ++it) {
        const int r0 = r0w + it * 4;
        const int o0 = __shfl(offv, it * 4 + 0), e0 = __shfl(offv, it * 4 + 1);
        const int o1 = e0,                       e1 = __shfl(offv, it * 4 + 2);
        const int o2 = e1,                       e2 = __shfl(offv, it * 4 + 3);
        const int o3 = e2,                       e3 = __shfl(offv, it * 4 + 4);
        const int d0 = e0 - o0, d1 = e1 - o1, d2 = e2 - o2, d3 = e3 - o3;

        float acc0 = (r0 + 0 < N_NODES) ? (float)x[(r0 + 0) * 64 + f] : 0.f;
        float acc1 = (r0 + 1 < N_NODES) ? (float)x[(r0 + 1) * 64 + f] : 0.f;
        float acc2 = (r0 + 2 < N_NODES) ? (float)x[(r0 + 2) * 64 + f] : 0.f;
        float acc3 = (r0 + 3 < N_NODES) ? (float)x[(r0 + 3) * 64 + f] : 0.f;

        int dmax = d0 > d1 ? d0 : d1;
        dmax = dmax > d2 ? dmax : d2;
        dmax = dmax > d3 ? dmax : d3;

        for (int base = 0; base < dmax; base += 64) {
            const int r0c = d0 - base, r1c = d1 - base;
            const int r2c = d2 - base, r3c = d3 - base;
            const int c0 = r0c <= 0 ? 0 : (r0c < 64 ? r0c : 64);
            const int c1 = r1c <= 0 ? 0 : (r1c < 64 ? r1c : 64);
            const int c2 = r2c <= 0 ? 0 : (r2c < 64 ? r2c : 64);
            const int c3 = r3c <= 0 ? 0 : (r3c < 64 ? r3c : 64);
            int s0 = 0, s1 = 0, s2 = 0, s3 = 0;
            if (f < c0) s0 = csr[o0 + base + f];
            if (f < c1) s1 = csr[o1 + base + f];
            if (f < c2) s2 = csr[o2 + base + f];
            if (f < c3) s3 = csr[o3 + base + f];

            int cmin = c0 < c1 ? c0 : c1;
            cmin = cmin < c2 ? cmin : c2;
            cmin = cmin < c3 ? cmin : c3;

            // interleaved 8-deep phase across all 4 streams (up to 32 in flight)
            int j = 0;
            for (; j + 8 <= cmin; j += 8) {
                GATHER8(s0, j, acc0)
                GATHER8(s1, j, acc1)
                GATHER8(s2, j, acc2)
                GATHER8(s3, j, acc3)
            }
            // interleaved 4-deep phase where all streams still qualify
            if (j + 4 <= cmin) {
                GATHER4(s0, j, acc0)
                GATHER4(s1, j, acc1)
                GATHER4(s2, j, acc2)
                GATHER4(s3, j, acc3)
                j += 4;
            }
            // per-stream tails
            int j0 = j, j1 = j, j2 = j, j3 = j;
            TAIL(s0, j0, c0, acc0)
            TAIL(s1, j1, c1, acc1)
            TAIL(s2, j2, c2, acc2)
            TAIL(s3, j3, c3, acc3)
        }
        const int lr = half * 8 + it * 4;
        hs[p][lr + 0][lane] = (bf16_t)acc0;
        hs[p][lr + 1][lane] = (bf16_t)acc1;
        hs[p][lr + 2][lane] = (bf16_t)acc2;
        hs[p][lr + 3][lane] = (bf16_t)acc3;
    }

    __syncthreads();   // gather done + weights visible

    // ---- GEMM1: read hs[p], write relu -> h2[p]; this wave owns ct = half*2 + {0,1}
    {
        bf16x8 af[2];
#pragma unroll
        for (int ks = 0; ks < 2; ++ks)
            af[ks] = *(const bf16x8*)(&hs[p][l15][ks * 32 + quad * 8]);
#pragma unroll
        for (int c = 0; c < 2; ++c) {
            const int ct = half * 2 + c;
            const bf16x8 b0 = *(const bf16x8*)&wfrag[0][ct * 2 + 0][lane][0];
            const bf16x8 b1 = *(const bf16x8*)&wfrag[0][ct * 2 + 1][lane][0];
            f32x4 acc = {0.f, 0.f, 0.f, 0.f};
            acc = __builtin_amdgcn_mfma_f32_16x16x32_bf16(af[0], b0, acc, 0, 0, 0);
            acc = __builtin_amdgcn_mfma_f32_16x16x32_bf16(af[1], b1, acc, 0, 0, 0);
            const float bv = biasA[ct * 16 + l15];
#pragma unroll
            for (int r = 0; r < 4; ++r) {
                float h = acc[r] + bv;
                h = h > 0.f ? h : 0.f;
                h2[p][quad * 4 + r][ct * 16 + l15] = (bf16_t)h;
            }
        }
    }

    __syncthreads();   // h1 complete

    // ---- GEMM2: read h2[p], write relu -> hs[p]
    {
        bf16x8 a2[2];
#pragma unroll
        for (int ks = 0; ks < 2; ++ks)
            a2[ks] = *(const bf16x8*)(&h2[p][l15][ks * 32 + quad * 8]);
#pragma unroll
        for (int c = 0; c < 2; ++c) {
            const int ct = half * 2 + c;
            const bf16x8 b0 = *(const bf16x8*)&wfrag[1][ct * 2 + 0][lane][0];
            const bf16x8 b1 = *(const bf16x8*)&wfrag[1][ct * 2 + 1][lane][0];
            f32x4 acc = {0.f, 0.f, 0.f, 0.f};
            acc = __builtin_amdgcn_mfma_f32_16x16x32_bf16(a2[0], b0, acc, 0, 0, 0);
            acc = __builtin_amdgcn_mfma_f32_16x16x32_bf16(a2[1], b1, acc, 0, 0, 0);
            const float bv = biasB[ct * 16 + l15];
#pragma unroll
            for (int r = 0; r < 4; ++r) {
                float h = acc[r] + bv;
                h = h > 0.f ? h : 0.f;
                hs[p][quad * 4 + r][ct * 16 + l15] = (bf16_t)h;
            }
        }
    }

    __syncthreads();   // h2 (final) complete

    if (POOL) {
        // segmented mean-pool numerator: one wave per pair scans its 16 rows
        if (half == 0) {
            int cur = -1;
            float acc = 0.f;
            for (int r = 0; r < 16; ++r) {
                const int row = rbp + r;
                if (row >= N_NODES) break;
                const int g = batch[row];           // wave-uniform
                const float v = (float)hs[p][r][lane];
                if (g != cur) {
                    if (cur >= 0) unsafeAtomicAdd(gsum + cur * 64 + lane, acc);
                    acc = 0.f;
                    cur = g;
                }
                acc += v;
            }
            if (cur >= 0) unsafeAtomicAdd(gsum + cur * 64 + lane, acc);
        }
    } else {
        // wave stores its 8 rows: one bf16x8 per lane
        const int row16 = half * 8 + (lane >> 3);
        const int colg  = (lane & 7) * 8;
        const int grow  = rbp + row16;
        const bf16x8 v = *(const bf16x8*)&hs[p][row16][colg];
        if (grow < N_NODES)
            *(bf16x8*)(xout + grow * 64 + colg) = v;
    }
}

// out[g][c] = (gsum[g]/max(cnt,1)) . wc[:,c] + bc[c]; cnt via binary search
__global__ void cls_kernel(const float* __restrict__ gsum,
                           const int* __restrict__ batch,
                           const float* __restrict__ wc, const float* __restrict__ bc,
                           float* __restrict__ out) {
    const int g = blockIdx.x;
    const int c = threadIdx.x;
    if (c >= N_CLS) return;
    int lo = 0, hi = N_NODES;
    while (lo < hi) { const int m = (lo + hi) >> 1; if (batch[m] < g) lo = m + 1; else hi = m; }
    const int lb = lo;
    lo = 0; hi = N_NODES;
    while (lo < hi) { const int m = (lo + hi) >> 1; if (batch[m] <= g) lo = m + 1; else hi = m; }
    const int cnt = lo - lb;
    const float inv = 1.f / (float)(cnt > 1 ? cnt : 1);
    float acc = bc[c];
    for (int k = 0; k < 64; ++k)
        acc += gsum[g * 64 + k] * inv * wc[k * N_CLS + c];
    out[g * N_CLS + c] = acc;
}

// ---------------------------------------------------------------------------
extern "C" void kernel_launch(void* const* d_in, const int* in_sizes, int n_in,
                              void* d_out, int out_size, void* d_ws, size_t ws_size,
                              hipStream_t stream) {
    const float* x   = (const float*)d_in[0];
    const float* w1a = (const float*)d_in[1];
    const float* b1a = (const float*)d_in[2];
    const float* w1b = (const float*)d_in[3];
    const float* b1b = (const float*)d_in[4];
    const float* w2a = (const float*)d_in[5];
    const float* b2a = (const float*)d_in[6];
    const float* w2b = (const float*)d_in[7];
    const float* b2b = (const float*)d_in[8];
    const float* w3a = (const float*)d_in[9];
    const float* b3a = (const float*)d_in[10];
    const float* w3b = (const float*)d_in[11];
    const float* b3b = (const float*)d_in[12];
    const float* wc  = (const float*)d_in[13];
    const float* bc  = (const float*)d_in[14];
    const int*   ei    = (const int*)d_in[15];
    const int*   batch = (const int*)d_in[16];
    float* out = (float*)d_out;

    // workspace layout (~50.1 MB, 16B-aligned)
    char*   ws     = (char*)d_ws;
    int*    bcnt   = (int*)ws;                      // 391 ints (pad 1568)
    int*    offset = (int*)(ws + 3136);             // N+1 ints (pad 400016)
    int*    csr    = (int*)(ws + 403152);           // E ints = 4,800,000
    int*    bpair  = (int*)(ws + 5203152);          // 391*4096*4 = 6,406,144
    bf16_t* xbf    = (bf16_t*)(ws + 11609296);      // 12,800,000
    bf16_t* h      = (bf16_t*)(ws + 24409296);      // 12,800,000
    bf16_t* xA     = (bf16_t*)(ws + 37209296);      // 12,800,000
    float*  gsum   = (float*)(ws + 50009296);       // 32,768

    const int e4grid = (N_EDGES / 4 + 255) / 256;   // 1172
    const int tiles  = (N_NODES + 63) / 64;         // 1563

    // x -> bf16 (+ zero bcnt/gsum)
    tobf_kernel<<<(N_NODES * 64) / (256 * 8), 256, 0, stream>>>(x, xbf, bcnt, gsum);

    // CSR build (once, reused 3x)
    binA_kernel<<<e4grid, 256, 0, stream>>>(ei, bcnt, bpair);
    sortfill_kernel<<<NBUCK, 256, 0, stream>>>(bpair, bcnt, offset, csr);

    // fused gather+MLP layers (ping-pong buffers: xbf -> xA -> h -> pool)
    gmlp_kernel<0><<<tiles, 512, 0, stream>>>(xbf, offset, csr, w1a, b1a, w1b, b1b, xA, nullptr, nullptr);
    gmlp_kernel<0><<<tiles, 512, 0, stream>>>(xA, offset, csr, w2a, b2a, w2b, b2b, h, nullptr, nullptr);
    gmlp_kernel<1><<<tiles, 512, 0, stream>>>(h, offset, csr, w3a, b3a, w3b, b3b, nullptr, batch, gsum);

    // classify
    cls_kernel<<<N_GRAPH, 64, 0, stream>>>(gsum, batch, wc, bc, out);
}

// Round 4
// 296.105 us; speedup vs baseline: 1.2293x; 1.2293x over previous
//
#include <hip/hip_runtime.h>
#include <hip/hip_bf16.h>

// GIN: 3x fused [CSR gather-sum + MLP(64->64->64) + relu] + mean-pool(128) + linear(64->10)
// gmlp v4: 128-thread blocks (2 waves = one 16-row MFMA tile), 6250 blocks.
//   Weights NOT in LDS: pre-packed bf16 fragments in global (prepped inside tobf),
//   read as broadcast 16B/lane loads (L1/L2-hit). LDS = 4.6KB/block -> 16 blocks/CU,
//   32-wave cap with deep refill; barriers sync only 2 sibling waves.
//   Dual-stream 8-deep gather per wave (r2 shape; r3 showed VGPR clamps serialize).
// CSR: 391-bucket binning + per-bucket counting sort w/ inline prefix.
// tobf zeroes bcnt/gsum + packs 3 layers' weight frags. 7 dispatches total.

#define N_NODES 100000
#define N_EDGES 1200000
#define N_GRAPH 128
#define N_CLS   10
#define NBUCK   391        // dst >> 8
#define BCAP    4096       // per-bucket capacity (mean 3070, +18 sigma)
#define BSH     12         // log2(BCAP)

typedef __bf16 bf16_t;
typedef __bf16 bf16x8 __attribute__((ext_vector_type(8)));
typedef float  f32x4  __attribute__((ext_vector_type(4)));

// ---------------- x -> bf16 (+ zero bcnt/gsum, + pack weight frags) ----------------
__global__ void tobf_kernel(const float* __restrict__ x, bf16_t* __restrict__ xb,
                            int* __restrict__ bcnt, float* __restrict__ gsum,
                            const float* __restrict__ w1a, const float* __restrict__ w1b,
                            const float* __restrict__ w2a, const float* __restrict__ w2b,
                            const float* __restrict__ w3a, const float* __restrict__ w3b,
                            bf16_t* __restrict__ wfragG) {
    const int tid = threadIdx.x;
    if (blockIdx.x == 0) {
        for (int i = tid; i < NBUCK; i += 256) bcnt[i] = 0;
    } else if (blockIdx.x == 1) {
        f32x4* g4 = (f32x4*)gsum;
        for (int i = tid; i < N_GRAPH * 16; i += 256)   // 8192 f32
            g4[i] = (f32x4){0.f, 0.f, 0.f, 0.f};
    } else if (blockIdx.x <= 4) {
        // pack layer L's weight fragments: wfragG[((L*2+m)*8+fi)*512 + lane*8 + j]
        const int L = blockIdx.x - 2;
        const float* wA = L == 0 ? w1a : (L == 1 ? w2a : w3a);
        const float* wB = L == 0 ? w1b : (L == 1 ? w2b : w3b);
        const int k  = tid >> 2;
        const int n0 = (tid & 3) << 4;
        const int ks = k >> 5, qd = (k >> 3) & 3, jj = k & 7;
        const int fi = ((n0 >> 4) << 1) + ks;
#pragma unroll
        for (int m = 0; m < 2; ++m) {
            const float* w = m ? wB : wA;
            const f32x4 v0 = *(const f32x4*)(w + k * 64 + n0);
            const f32x4 v1 = *(const f32x4*)(w + k * 64 + n0 + 4);
            const f32x4 v2 = *(const f32x4*)(w + k * 64 + n0 + 8);
            const f32x4 v3 = *(const f32x4*)(w + k * 64 + n0 + 12);
            bf16_t* dst = wfragG + ((L * 2 + m) * 8 + fi) * 512 + jj;
#pragma unroll
            for (int l = 0; l < 4; ++l) {
                dst[(qd * 16 + l) * 8]      = (bf16_t)v0[l];
                dst[(qd * 16 + 4 + l) * 8]  = (bf16_t)v1[l];
                dst[(qd * 16 + 8 + l) * 8]  = (bf16_t)v2[l];
                dst[(qd * 16 + 12 + l) * 8] = (bf16_t)v3[l];
            }
        }
    }
    const int i = (blockIdx.x * 256 + tid) * 8;
    const f32x4 a = *(const f32x4*)(x + i);
    const f32x4 b = *(const f32x4*)(x + i + 4);
    bf16x8 o;
#pragma unroll
    for (int j = 0; j < 4; ++j) { o[j] = (bf16_t)a[j]; o[4 + j] = (bf16_t)b[j]; }
    *(bf16x8*)(xb + i) = o;
}

// ---------------- CSR build ----------------
__global__ void binA_kernel(const int* __restrict__ ei,
                            int* __restrict__ bcnt,
                            int* __restrict__ bpair) {
    __shared__ int lcnt[NBUCK];
    __shared__ int lbase[NBUCK];
    const int t = threadIdx.x;
    for (int b = t; b < NBUCK; b += 256) lcnt[b] = 0;
    __syncthreads();
    const int e0 = (blockIdx.x * 256 + t) * 4;
    int4 s4, d4; int b[4], r[4];
    const bool valid = e0 < N_EDGES;               // N_EDGES % 4 == 0
    if (valid) {
        s4 = *(const int4*)(ei + e0);
        d4 = *(const int4*)(ei + N_EDGES + e0);
        b[0] = d4.x >> 8; b[1] = d4.y >> 8; b[2] = d4.z >> 8; b[3] = d4.w >> 8;
        r[0] = atomicAdd(&lcnt[b[0]], 1);
        r[1] = atomicAdd(&lcnt[b[1]], 1);
        r[2] = atomicAdd(&lcnt[b[2]], 1);
        r[3] = atomicAdd(&lcnt[b[3]], 1);
    }
    __syncthreads();
    for (int bb = t; bb < NBUCK; bb += 256) {
        const int c = lcnt[bb];
        lbase[bb] = c ? atomicAdd(&bcnt[bb], c) : 0;
    }
    __syncthreads();
    if (valid) {
        const int ss[4] = {s4.x, s4.y, s4.z, s4.w};
        const int dd[4] = {d4.x, d4.y, d4.z, d4.w};
#pragma unroll
        for (int j = 0; j < 4; ++j) {
            const int slot = lbase[b[j]] + r[j];
            if (slot < BCAP)
                bpair[(b[j] << BSH) + slot] = (ss[j] << 8) | (dd[j] & 255);
        }
    }
}

// one WG per bucket: inline prefix over min(bcnt,BCAP) + LDS counting sort
__global__ void sortfill_kernel(const int* __restrict__ bpair,
                                const int* __restrict__ bcnt,
                                int* __restrict__ offset, int* __restrict__ csr) {
    __shared__ int red[256];
    __shared__ int hist[256];
    __shared__ int l[256];
    __shared__ int cursor[256];
    const int b = blockIdx.x;
    const int t = threadIdx.x;
    const int base = b << BSH;

    // prefix: cbase = sum_{i<b} min(bcnt[i],BCAP); cnt = min(bcnt[b],BCAP)
    int part = 0;
    for (int i = t; i < b; i += 256) {
        int c = bcnt[i];
        part += (c < BCAP ? c : BCAP);
    }
    red[t] = part;
    __syncthreads();
    for (int d = 128; d > 0; d >>= 1) {
        if (t < d) red[t] += red[t + d];
        __syncthreads();
    }
    const int cbase = red[0];
    int cnt = bcnt[b];
    cnt = cnt < BCAP ? cnt : BCAP;
    if (b == NBUCK - 1 && t == 0) offset[N_NODES] = cbase + cnt;
    __syncthreads();

    hist[t] = 0;
    __syncthreads();
    for (int i = t; i < cnt; i += 256)
        atomicAdd(&hist[bpair[base + i] & 255], 1);
    __syncthreads();

    const int v = hist[t];
    l[t] = v;
    __syncthreads();
    for (int d = 1; d < 256; d <<= 1) {
        int u = l[t];
        if (t >= d) u += l[t - d];
        __syncthreads();
        l[t] = u;
        __syncthreads();
    }
    const int gpos = cbase + l[t] - v;              // exclusive
    const int node = (b << 8) + t;
    if (node < N_NODES) offset[node] = gpos;
    cursor[t] = gpos;
    __syncthreads();

    for (int i = t; i < cnt; i += 256) {
        const int p = bpair[base + i];
        const int pos = atomicAdd(&cursor[p & 255], 1);
        csr[pos] = p >> 8;
    }
}

// ---------------------------------------------------------------------------
// Dual-stream gather macros: two independent 8-deep load pipelines per wave.
// ---------------------------------------------------------------------------
#define GATHER8(S, J, ACC)                                                     \
    {                                                                          \
        const int t0 = __shfl(S, J + 0), t1 = __shfl(S, J + 1);                \
        const int t2 = __shfl(S, J + 2), t3 = __shfl(S, J + 3);                \
        const int t4 = __shfl(S, J + 4), t5 = __shfl(S, J + 5);                \
        const int t6 = __shfl(S, J + 6), t7 = __shfl(S, J + 7);                \
        const float u0 = (float)x[t0 * 64 + f], u1 = (float)x[t1 * 64 + f];    \
        const float u2 = (float)x[t2 * 64 + f], u3 = (float)x[t3 * 64 + f];    \
        const float u4 = (float)x[t4 * 64 + f], u5 = (float)x[t5 * 64 + f];    \
        const float u6 = (float)x[t6 * 64 + f], u7 = (float)x[t7 * 64 + f];    \
        ACC += ((u0 + u1) + (u2 + u3)) + ((u4 + u5) + (u6 + u7));              \
    }
#define GATHER4(S, J, ACC)                                                     \
    {                                                                          \
        const int t0 = __shfl(S, J + 0), t1 = __shfl(S, J + 1);                \
        const int t2 = __shfl(S, J + 2), t3 = __shfl(S, J + 3);                \
        const float u0 = (float)x[t0 * 64 + f], u1 = (float)x[t1 * 64 + f];    \
        const float u2 = (float)x[t2 * 64 + f], u3 = (float)x[t3 * 64 + f];    \
        ACC += (u0 + u1) + (u2 + u3);                                          \
    }

// ---------------------------------------------------------------------------
// Fused gather + MLP, one 16-row tile per 128-thread block (2 waves).
// Wave half=wv gathers 8 rows (local rows half*8..half*8+7) dual-stream into hs;
// then each wave computes 2 of 4 col-tiles of the 16x64 MLP. Weight B-fragments
// and biases come straight from global (wf: pre-packed bf16; broadcast loads).
// POOL=1 (layer 3): each wave emits segmented mean-pool numerator atomics for
// its own 8 rows.
// ---------------------------------------------------------------------------
template <int POOL>
__global__ void gmlp_kernel(const bf16_t* __restrict__ x,
                            const int* __restrict__ offset,
                            const int* __restrict__ csr,
                            const bf16_t* __restrict__ wf,   // [m*8+fi][lane][8] bf16
                            const float* __restrict__ ba, const float* __restrict__ bb,
                            bf16_t* __restrict__ xout,
                            const int* __restrict__ batch,
                            float* __restrict__ gsum) {
    __shared__ __align__(16) bf16_t hs[16][72];   // agg rows, then h2 (final)
    __shared__ __align__(16) bf16_t h2[16][72];   // h1 (GEMM1 out)

    const int tid  = threadIdx.x;
    const int half = tid >> 6;          // 0..1
    const int lane = tid & 63;
    const int l15  = lane & 15;
    const int quad = lane >> 4;

    const int rb  = blockIdx.x * 16;    // tile's first row (N_NODES % 16 == 0)
    const int r0w = rb + half * 8;      // this wave's first row
    const int f   = lane;

    // prefetch the 9 offsets this wave needs (rows r0w..r0w+8), broadcast via shfl
    int offv = 0;
    if (lane < 9) offv = offset[r0w + lane];

    // ---- gather 8 rows into hs (dual pipeline: local rows half*8+i, +4) ----
    for (int i = 0; i < 4; ++i) {
        const int nA = r0w + i;
        const int nB = r0w + i + 4;
        const int oA = __shfl(offv, i),     eA = __shfl(offv, i + 1);
        const int oB = __shfl(offv, i + 4), eB = __shfl(offv, i + 5);
        const int dA = eA - oA, dB = eB - oB;

        float accA = (float)x[nA * 64 + f];
        float accB = (float)x[nB * 64 + f];

        for (int base = 0; base < dA || base < dB; base += 64) {
            const int ra = dA - base, rb2 = dB - base;
            const int cntA = ra <= 0 ? 0 : (ra < 64 ? ra : 64);
            const int cntB = rb2 <= 0 ? 0 : (rb2 < 64 ? rb2 : 64);
            int sA = 0, sB = 0;
            if (f < cntA) sA = csr[oA + base + f];
            if (f < cntB) sB = csr[oB + base + f];

            int j = 0;
            for (; j + 8 <= cntA && j + 8 <= cntB; j += 8) {
                GATHER8(sA, j, accA)
                GATHER8(sB, j, accB)
            }
            int jA = j, jB = j;
            for (; jA + 8 <= cntA; jA += 8) { GATHER8(sA, jA, accA) }
            for (; jB + 8 <= cntB; jB += 8) { GATHER8(sB, jB, accB) }
            if (jA + 4 <= cntA && jB + 4 <= cntB) {
                GATHER4(sA, jA, accA)
                GATHER4(sB, jB, accB)
                jA += 4; jB += 4;
            }
            if (jA + 4 <= cntA) { GATHER4(sA, jA, accA) jA += 4; }
            if (jB + 4 <= cntB) { GATHER4(sB, jB, accB) jB += 4; }
            for (; jA < cntA; ++jA) { const int t = __shfl(sA, jA); accA += (float)x[t * 64 + f]; }
            for (; jB < cntB; ++jB) { const int t = __shfl(sB, jB); accB += (float)x[t * 64 + f]; }
        }
        hs[half * 8 + i][lane]     = (bf16_t)accA;
        hs[half * 8 + i + 4][lane] = (bf16_t)accB;
    }

    __syncthreads();   // gather done

    // ---- GEMM1: read hs, write relu -> h2; this wave owns ct = half*2 + {0,1}
    {
        bf16x8 af[2];
#pragma unroll
        for (int ks = 0; ks < 2; ++ks)
            af[ks] = *(const bf16x8*)(&hs[l15][ks * 32 + quad * 8]);
#pragma unroll
        for (int c = 0; c < 2; ++c) {
            const int ct = half * 2 + c;
            const bf16x8 b0 = *(const bf16x8*)(wf + (0 * 8 + ct * 2 + 0) * 512 + lane * 8);
            const bf16x8 b1 = *(const bf16x8*)(wf + (0 * 8 + ct * 2 + 1) * 512 + lane * 8);
            f32x4 acc = {0.f, 0.f, 0.f, 0.f};
            acc = __builtin_amdgcn_mfma_f32_16x16x32_bf16(af[0], b0, acc, 0, 0, 0);
            acc = __builtin_amdgcn_mfma_f32_16x16x32_bf16(af[1], b1, acc, 0, 0, 0);
            const float bv = ba[ct * 16 + l15];
#pragma unroll
            for (int r = 0; r < 4; ++r) {
                float h = acc[r] + bv;
                h = h > 0.f ? h : 0.f;
                h2[quad * 4 + r][ct * 16 + l15] = (bf16_t)h;
            }
        }
    }

    __syncthreads();   // h1 complete

    // ---- GEMM2: read h2, write relu -> hs
    {
        bf16x8 a2[2];
#pragma unroll
        for (int ks = 0; ks < 2; ++ks)
            a2[ks] = *(const bf16x8*)(&h2[l15][ks * 32 + quad * 8]);
#pragma unroll
        for (int c = 0; c < 2; ++c) {
            const int ct = half * 2 + c;
            const bf16x8 b0 = *(const bf16x8*)(wf + (1 * 8 + ct * 2 + 0) * 512 + lane * 8);
            const bf16x8 b1 = *(const bf16x8*)(wf + (1 * 8 + ct * 2 + 1) * 512 + lane * 8);
            f32x4 acc = {0.f, 0.f, 0.f, 0.f};
            acc = __builtin_amdgcn_mfma_f32_16x16x32_bf16(a2[0], b0, acc, 0, 0, 0);
            acc = __builtin_amdgcn_mfma_f32_16x16x32_bf16(a2[1], b1, acc, 0, 0, 0);
            const float bv = bb[ct * 16 + l15];
#pragma unroll
            for (int r = 0; r < 4; ++r) {
                float h = acc[r] + bv;
                h = h > 0.f ? h : 0.f;
                hs[quad * 4 + r][ct * 16 + l15] = (bf16_t)h;
            }
        }
    }

    __syncthreads();   // final h complete

    if (POOL) {
        // segmented mean-pool numerator: each wave scans its own 8 rows
        int cur = -1;
        float acc = 0.f;
        for (int r = 0; r < 8; ++r) {
            const int row = r0w + r;
            const int g = batch[row];           // wave-uniform
            const float v = (float)hs[half * 8 + r][lane];
            if (g != cur) {
                if (cur >= 0) unsafeAtomicAdd(gsum + cur * 64 + lane, acc);
                acc = 0.f;
                cur = g;
            }
            acc += v;
        }
        if (cur >= 0) unsafeAtomicAdd(gsum + cur * 64 + lane, acc);
    } else {
        // wave stores its 8 rows: one bf16x8 per lane
        const int row16 = half * 8 + (lane >> 3);
        const int colg  = (lane & 7) * 8;
        const bf16x8 v = *(const bf16x8*)&hs[row16][colg];
        *(bf16x8*)(xout + (rb + row16) * 64 + colg) = v;
    }
}

// out[g][c] = (gsum[g]/max(cnt,1)) . wc[:,c] + bc[c]; cnt via binary search
__global__ void cls_kernel(const float* __restrict__ gsum,
                           const int* __restrict__ batch,
                           const float* __restrict__ wc, const float* __restrict__ bc,
                           float* __restrict__ out) {
    const int g = blockIdx.x;
    const int c = threadIdx.x;
    if (c >= N_CLS) return;
    int lo = 0, hi = N_NODES;
    while (lo < hi) { const int m = (lo + hi) >> 1; if (batch[m] < g) lo = m + 1; else hi = m; }
    const int lb = lo;
    lo = 0; hi = N_NODES;
    while (lo < hi) { const int m = (lo + hi) >> 1; if (batch[m] <= g) lo = m + 1; else hi = m; }
    const int cnt = lo - lb;
    const float inv = 1.f / (float)(cnt > 1 ? cnt : 1);
    float acc = bc[c];
    for (int k = 0; k < 64; ++k)
        acc += gsum[g * 64 + k] * inv * wc[k * N_CLS + c];
    out[g * N_CLS + c] = acc;
}

// ---------------------------------------------------------------------------
extern "C" void kernel_launch(void* const* d_in, const int* in_sizes, int n_in,
                              void* d_out, int out_size, void* d_ws, size_t ws_size,
                              hipStream_t stream) {
    const float* x   = (const float*)d_in[0];
    const float* w1a = (const float*)d_in[1];
    const float* b1a = (const float*)d_in[2];
    const float* w1b = (const float*)d_in[3];
    const float* b1b = (const float*)d_in[4];
    const float* w2a = (const float*)d_in[5];
    const float* b2a = (const float*)d_in[6];
    const float* w2b = (const float*)d_in[7];
    const float* b2b = (const float*)d_in[8];
    const float* w3a = (const float*)d_in[9];
    const float* b3a = (const float*)d_in[10];
    const float* w3b = (const float*)d_in[11];
    const float* b3b = (const float*)d_in[12];
    const float* wc  = (const float*)d_in[13];
    const float* bc  = (const float*)d_in[14];
    const int*   ei    = (const int*)d_in[15];
    const int*   batch = (const int*)d_in[16];
    float* out = (float*)d_out;

    // workspace layout (~50.1 MB, 16B-aligned)
    char*   ws     = (char*)d_ws;
    int*    bcnt   = (int*)ws;                      // 391 ints (pad 1568)
    int*    offset = (int*)(ws + 3136);             // N+1 ints (pad 400016)
    int*    csr    = (int*)(ws + 403152);           // E ints = 4,800,000
    int*    bpair  = (int*)(ws + 5203152);          // 391*4096*4 = 6,406,144
    bf16_t* xbf    = (bf16_t*)(ws + 11609296);      // 12,800,000
    bf16_t* h      = (bf16_t*)(ws + 24409296);      // 12,800,000
    bf16_t* xA     = (bf16_t*)(ws + 37209296);      // 12,800,000
    float*  gsum   = (float*)(ws + 50009296);       // 32,768
    bf16_t* wfragG = (bf16_t*)(ws + 50042064);      // 3*2*8*512 bf16 = 49,152 B

    const int e4grid = (N_EDGES / 4 + 255) / 256;   // 1172
    const int tiles  = N_NODES / 16;                // 6250 (exact)

    // x -> bf16 (+ zero bcnt/gsum, pack weight frags)
    tobf_kernel<<<(N_NODES * 64) / (256 * 8), 256, 0, stream>>>(
        x, xbf, bcnt, gsum, w1a, w1b, w2a, w2b, w3a, w3b, wfragG);

    // CSR build (once, reused 3x)
    binA_kernel<<<e4grid, 256, 0, stream>>>(ei, bcnt, bpair);
    sortfill_kernel<<<NBUCK, 256, 0, stream>>>(bpair, bcnt, offset, csr);

    // fused gather+MLP layers (ping-pong buffers: xbf -> xA -> h -> pool)
    gmlp_kernel<0><<<tiles, 128, 0, stream>>>(xbf, offset, csr, wfragG,        b1a, b1b, xA, nullptr, nullptr);
    gmlp_kernel<0><<<tiles, 128, 0, stream>>>(xA,  offset, csr, wfragG + 8192, b2a, b2b, h,  nullptr, nullptr);
    gmlp_kernel<1><<<tiles, 128, 0, stream>>>(h,   offset, csr, wfragG + 16384, b3a, b3b, nullptr, batch, gsum);

    // classify
    cls_kernel<<<N_GRAPH, 64, 0, stream>>>(gsum, batch, wc, bc, out);
}

// Round 5
// 287.725 us; speedup vs baseline: 1.2651x; 1.0291x over previous
//
#include <hip/hip_runtime.h>
#include <hip/hip_bf16.h>

// GIN: 3x fused [CSR gather-sum + MLP(64->64->64) + relu] + mean-pool(128) + linear(64->10)
// gmlp v5: 128-thread blocks (2 waves = one 16-row MFMA tile), 6250 blocks.
//   Gather: zero-pad row N_NODES in every feature buffer -> partial groups run as
//   full unmasked GATHER8s (no GATHER4/scalar tails = no serial dependent loads);
//   all 8 csr index vectors preloaded up front. Dual stream, ~16 loads in flight.
//   Weights pre-packed bf16 in global (broadcast 16B loads); LDS 4.6KB/block.
// CSR: 391-bucket binning + per-bucket counting sort w/ inline prefix.
// tobf zeroes bcnt/gsum/pad-rows + packs 3 layers' weight frags. 7 dispatches.

#define N_NODES 100000
#define N_EDGES 1200000
#define N_GRAPH 128
#define N_CLS   10
#define NBUCK   391        // dst >> 8
#define BCAP    4096       // per-bucket capacity (mean 3070, +18 sigma)
#define BSH     12         // log2(BCAP)

typedef __bf16 bf16_t;
typedef __bf16 bf16x8 __attribute__((ext_vector_type(8)));
typedef float  f32x4  __attribute__((ext_vector_type(4)));

// ---------------- x -> bf16 (+ zero bcnt/gsum/pads, + pack weight frags) ----------------
__global__ void tobf_kernel(const float* __restrict__ x, bf16_t* __restrict__ xb,
                            int* __restrict__ bcnt, float* __restrict__ gsum,
                            const float* __restrict__ w1a, const float* __restrict__ w1b,
                            const float* __restrict__ w2a, const float* __restrict__ w2b,
                            const float* __restrict__ w3a, const float* __restrict__ w3b,
                            bf16_t* __restrict__ wfragG,
                            bf16_t* __restrict__ hPad, bf16_t* __restrict__ xAPad) {
    const int tid = threadIdx.x;
    if (blockIdx.x == 0) {
        for (int i = tid; i < NBUCK; i += 256) bcnt[i] = 0;
    } else if (blockIdx.x == 1) {
        f32x4* g4 = (f32x4*)gsum;
        for (int i = tid; i < N_GRAPH * 16; i += 256)   // 8192 f32
            g4[i] = (f32x4){0.f, 0.f, 0.f, 0.f};
        if (tid < 64) {                                  // zero-pad rows (idx N_NODES)
            xb[N_NODES * 64 + tid]    = (bf16_t)0.f;
            hPad[N_NODES * 64 + tid]  = (bf16_t)0.f;
            xAPad[N_NODES * 64 + tid] = (bf16_t)0.f;
        }
    } else if (blockIdx.x <= 4) {
        // pack layer L's weight fragments: wfragG[((L*2+m)*8+fi)*512 + lane*8 + j]
        const int L = blockIdx.x - 2;
        const float* wA = L == 0 ? w1a : (L == 1 ? w2a : w3a);
        const float* wB = L == 0 ? w1b : (L == 1 ? w2b : w3b);
        const int k  = tid >> 2;
        const int n0 = (tid & 3) << 4;
        const int ks = k >> 5, qd = (k >> 3) & 3, jj = k & 7;
        const int fi = ((n0 >> 4) << 1) + ks;
#pragma unroll
        for (int m = 0; m < 2; ++m) {
            const float* w = m ? wB : wA;
            const f32x4 v0 = *(const f32x4*)(w + k * 64 + n0);
            const f32x4 v1 = *(const f32x4*)(w + k * 64 + n0 + 4);
            const f32x4 v2 = *(const f32x4*)(w + k * 64 + n0 + 8);
            const f32x4 v3 = *(const f32x4*)(w + k * 64 + n0 + 12);
            bf16_t* dst = wfragG + ((L * 2 + m) * 8 + fi) * 512 + jj;
#pragma unroll
            for (int l = 0; l < 4; ++l) {
                dst[(qd * 16 + l) * 8]      = (bf16_t)v0[l];
                dst[(qd * 16 + 4 + l) * 8]  = (bf16_t)v1[l];
                dst[(qd * 16 + 8 + l) * 8]  = (bf16_t)v2[l];
                dst[(qd * 16 + 12 + l) * 8] = (bf16_t)v3[l];
            }
        }
    }
    const int i = (blockIdx.x * 256 + tid) * 8;
    const f32x4 a = *(const f32x4*)(x + i);
    const f32x4 b = *(const f32x4*)(x + i + 4);
    bf16x8 o;
#pragma unroll
    for (int j = 0; j < 4; ++j) { o[j] = (bf16_t)a[j]; o[4 + j] = (bf16_t)b[j]; }
    *(bf16x8*)(xb + i) = o;
}

// ---------------- CSR build ----------------
__global__ void binA_kernel(const int* __restrict__ ei,
                            int* __restrict__ bcnt,
                            int* __restrict__ bpair) {
    __shared__ int lcnt[NBUCK];
    __shared__ int lbase[NBUCK];
    const int t = threadIdx.x;
    for (int b = t; b < NBUCK; b += 256) lcnt[b] = 0;
    __syncthreads();
    const int e0 = (blockIdx.x * 256 + t) * 4;
    int4 s4, d4; int b[4], r[4];
    const bool valid = e0 < N_EDGES;               // N_EDGES % 4 == 0
    if (valid) {
        s4 = *(const int4*)(ei + e0);
        d4 = *(const int4*)(ei + N_EDGES + e0);
        b[0] = d4.x >> 8; b[1] = d4.y >> 8; b[2] = d4.z >> 8; b[3] = d4.w >> 8;
        r[0] = atomicAdd(&lcnt[b[0]], 1);
        r[1] = atomicAdd(&lcnt[b[1]], 1);
        r[2] = atomicAdd(&lcnt[b[2]], 1);
        r[3] = atomicAdd(&lcnt[b[3]], 1);
    }
    __syncthreads();
    for (int bb = t; bb < NBUCK; bb += 256) {
        const int c = lcnt[bb];
        lbase[bb] = c ? atomicAdd(&bcnt[bb], c) : 0;
    }
    __syncthreads();
    if (valid) {
        const int ss[4] = {s4.x, s4.y, s4.z, s4.w};
        const int dd[4] = {d4.x, d4.y, d4.z, d4.w};
#pragma unroll
        for (int j = 0; j < 4; ++j) {
            const int slot = lbase[b[j]] + r[j];
            if (slot < BCAP)
                bpair[(b[j] << BSH) + slot] = (ss[j] << 8) | (dd[j] & 255);
        }
    }
}

// one WG per bucket: inline prefix over min(bcnt,BCAP) + LDS counting sort
__global__ void sortfill_kernel(const int* __restrict__ bpair,
                                const int* __restrict__ bcnt,
                                int* __restrict__ offset, int* __restrict__ csr) {
    __shared__ int red[256];
    __shared__ int hist[256];
    __shared__ int l[256];
    __shared__ int cursor[256];
    const int b = blockIdx.x;
    const int t = threadIdx.x;
    const int base = b << BSH;

    // prefix: cbase = sum_{i<b} min(bcnt[i],BCAP); cnt = min(bcnt[b],BCAP)
    int part = 0;
    for (int i = t; i < b; i += 256) {
        int c = bcnt[i];
        part += (c < BCAP ? c : BCAP);
    }
    red[t] = part;
    __syncthreads();
    for (int d = 128; d > 0; d >>= 1) {
        if (t < d) red[t] += red[t + d];
        __syncthreads();
    }
    const int cbase = red[0];
    int cnt = bcnt[b];
    cnt = cnt < BCAP ? cnt : BCAP;
    if (b == NBUCK - 1 && t == 0) offset[N_NODES] = cbase + cnt;
    __syncthreads();

    hist[t] = 0;
    __syncthreads();
    for (int i = t; i < cnt; i += 256)
        atomicAdd(&hist[bpair[base + i] & 255], 1);
    __syncthreads();

    const int v = hist[t];
    l[t] = v;
    __syncthreads();
    for (int d = 1; d < 256; d <<= 1) {
        int u = l[t];
        if (t >= d) u += l[t - d];
        __syncthreads();
        l[t] = u;
        __syncthreads();
    }
    const int gpos = cbase + l[t] - v;              // exclusive
    const int node = (b << 8) + t;
    if (node < N_NODES) offset[node] = gpos;
    cursor[t] = gpos;
    __syncthreads();

    for (int i = t; i < cnt; i += 256) {
        const int p = bpair[base + i];
        const int pos = atomicAdd(&cursor[p & 255], 1);
        csr[pos] = p >> 8;
    }
}

// ---------------------------------------------------------------------------
// Unmasked 8-deep gather group. Indices beyond a row's count are N_NODES ->
// the zero pad row (L1-hot, contributes 0).
// ---------------------------------------------------------------------------
#define G8(S, J, ACC)                                                          \
    {                                                                          \
        const int t0 = __shfl(S, (J) + 0), t1 = __shfl(S, (J) + 1);            \
        const int t2 = __shfl(S, (J) + 2), t3 = __shfl(S, (J) + 3);            \
        const int t4 = __shfl(S, (J) + 4), t5 = __shfl(S, (J) + 5);            \
        const int t6 = __shfl(S, (J) + 6), t7 = __shfl(S, (J) + 7);            \
        const float u0 = (float)x[t0 * 64 + f], u1 = (float)x[t1 * 64 + f];    \
        const float u2 = (float)x[t2 * 64 + f], u3 = (float)x[t3 * 64 + f];    \
        const float u4 = (float)x[t4 * 64 + f], u5 = (float)x[t5 * 64 + f];    \
        const float u6 = (float)x[t6 * 64 + f], u7 = (float)x[t7 * 64 + f];    \
        ACC += ((u0 + u1) + (u2 + u3)) + ((u4 + u5) + (u6 + u7));              \
    }

// one dual-stream row pair: rows r0w+I (A) and r0w+I+4 (B)
#define ROWPAIR(I, SA, CA, DA, OA, SB, CB, DB, OB)                             \
    {                                                                          \
        float accA = (float)x[(r0w + I) * 64 + f];                             \
        float accB = (float)x[(r0w + I + 4) * 64 + f];                         \
        const int cmax = (CA) > (CB) ? (CA) : (CB);                            \
        for (int j = 0; j < cmax; j += 8) {                                    \
            if (j < (CA)) { G8(SA, j, accA) }                                  \
            if (j < (CB)) { G8(SB, j, accB) }                                  \
        }                                                                      \
        if ((DA) > 64 || (DB) > 64) {       /* rare long rows */               \
            for (int base = 64; base < (DA) || base < (DB); base += 64) {      \
                const int ra = (DA) - base, rb2 = (DB) - base;                 \
                const int ca2 = ra <= 0 ? 0 : (ra < 64 ? ra : 64);             \
                const int cb2 = rb2 <= 0 ? 0 : (rb2 < 64 ? rb2 : 64);          \
                int sA2 = N_NODES, sB2 = N_NODES;                              \
                if (f < ca2) sA2 = csr[(OA) + base + f];                       \
                if (f < cb2) sB2 = csr[(OB) + base + f];                       \
                const int cm2 = ca2 > cb2 ? ca2 : cb2;                         \
                for (int j = 0; j < cm2; j += 8) {                             \
                    if (j < ca2) { G8(sA2, j, accA) }                          \
                    if (j < cb2) { G8(sB2, j, accB) }                          \
                }                                                              \
            }                                                                  \
        }                                                                      \
        hs[half * 8 + I][lane]     = (bf16_t)accA;                             \
        hs[half * 8 + I + 4][lane] = (bf16_t)accB;                             \
    }

// ---------------------------------------------------------------------------
// Fused gather + MLP, one 16-row tile per 128-thread block (2 waves).
// Wave half gathers 8 rows (4 dual-stream pairs, csr indices all preloaded);
// each wave computes 2 of 4 col-tiles of the 16x64 MLP. Weight B-fragments and
// biases from global (wf: pre-packed bf16; broadcast loads).
// POOL=1 (layer 3): each wave emits segmented mean-pool numerator atomics.
// ---------------------------------------------------------------------------
template <int POOL>
__global__ void gmlp_kernel(const bf16_t* __restrict__ x,
                            const int* __restrict__ offset,
                            const int* __restrict__ csr,
                            const bf16_t* __restrict__ wf,   // [m*8+fi][lane][8] bf16
                            const float* __restrict__ ba, const float* __restrict__ bb,
                            bf16_t* __restrict__ xout,
                            const int* __restrict__ batch,
                            float* __restrict__ gsum) {
    __shared__ __align__(16) bf16_t hs[16][72];   // agg rows, then h2 (final)
    __shared__ __align__(16) bf16_t h2[16][72];   // h1 (GEMM1 out)

    const int tid  = threadIdx.x;
    const int half = tid >> 6;          // 0..1
    const int lane = tid & 63;
    const int l15  = lane & 15;
    const int quad = lane >> 4;

    const int rb  = blockIdx.x * 16;    // tile's first row (N_NODES % 16 == 0)
    const int r0w = rb + half * 8;      // this wave's first row
    const int f   = lane;

    // prefetch the 9 offsets this wave needs, broadcast via readlane-shfl
    int offv = 0;
    if (lane < 9) offv = offset[r0w + lane];
    const int o0 = __shfl(offv, 0), o1 = __shfl(offv, 1), o2 = __shfl(offv, 2);
    const int o3 = __shfl(offv, 3), o4 = __shfl(offv, 4), o5 = __shfl(offv, 5);
    const int o6 = __shfl(offv, 6), o7 = __shfl(offv, 7), o8 = __shfl(offv, 8);
    const int d0 = o1 - o0, d1 = o2 - o1, d2 = o3 - o2, d3 = o4 - o3;
    const int d4 = o5 - o4, d5 = o6 - o5, d6 = o7 - o6, d7 = o8 - o7;
    const int c0 = d0 < 64 ? d0 : 64, c1 = d1 < 64 ? d1 : 64;
    const int c2 = d2 < 64 ? d2 : 64, c3 = d3 < 64 ? d3 : 64;
    const int c4 = d4 < 64 ? d4 : 64, c5 = d5 < 64 ? d5 : 64;
    const int c6 = d6 < 64 ? d6 : 64, c7 = d7 < 64 ? d7 : 64;

    // preload all 8 rows' first-chunk csr index vectors (8 coalesced loads in flight)
    int s0 = N_NODES, s1 = N_NODES, s2 = N_NODES, s3 = N_NODES;
    int s4 = N_NODES, s5 = N_NODES, s6 = N_NODES, s7 = N_NODES;
    if (f < c0) s0 = csr[o0 + f];
    if (f < c1) s1 = csr[o1 + f];
    if (f < c2) s2 = csr[o2 + f];
    if (f < c3) s3 = csr[o3 + f];
    if (f < c4) s4 = csr[o4 + f];
    if (f < c5) s5 = csr[o5 + f];
    if (f < c6) s6 = csr[o6 + f];
    if (f < c7) s7 = csr[o7 + f];

    // ---- gather 8 rows into hs (pairs (i, i+4); all groups full G8) ----
    ROWPAIR(0, s0, c0, d0, o0, s4, c4, d4, o4)
    ROWPAIR(1, s1, c1, d1, o1, s5, c5, d5, o5)
    ROWPAIR(2, s2, c2, d2, o2, s6, c6, d6, o6)
    ROWPAIR(3, s3, c3, d3, o3, s7, c7, d7, o7)

    __syncthreads();   // gather done

    // ---- GEMM1: read hs, write relu -> h2; this wave owns ct = half*2 + {0,1}
    {
        bf16x8 af[2];
#pragma unroll
        for (int ks = 0; ks < 2; ++ks)
            af[ks] = *(const bf16x8*)(&hs[l15][ks * 32 + quad * 8]);
#pragma unroll
        for (int c = 0; c < 2; ++c) {
            const int ct = half * 2 + c;
            const bf16x8 b0 = *(const bf16x8*)(wf + (0 * 8 + ct * 2 + 0) * 512 + lane * 8);
            const bf16x8 b1 = *(const bf16x8*)(wf + (0 * 8 + ct * 2 + 1) * 512 + lane * 8);
            f32x4 acc = {0.f, 0.f, 0.f, 0.f};
            acc = __builtin_amdgcn_mfma_f32_16x16x32_bf16(af[0], b0, acc, 0, 0, 0);
            acc = __builtin_amdgcn_mfma_f32_16x16x32_bf16(af[1], b1, acc, 0, 0, 0);
            const float bv = ba[ct * 16 + l15];
#pragma unroll
            for (int r = 0; r < 4; ++r) {
                float h = acc[r] + bv;
                h = h > 0.f ? h : 0.f;
                h2[quad * 4 + r][ct * 16 + l15] = (bf16_t)h;
            }
        }
    }

    __syncthreads();   // h1 complete

    // ---- GEMM2: read h2, write relu -> hs
    {
        bf16x8 a2[2];
#pragma unroll
        for (int ks = 0; ks < 2; ++ks)
            a2[ks] = *(const bf16x8*)(&h2[l15][ks * 32 + quad * 8]);
#pragma unroll
        for (int c = 0; c < 2; ++c) {
            const int ct = half * 2 + c;
            const bf16x8 b0 = *(const bf16x8*)(wf + (1 * 8 + ct * 2 + 0) * 512 + lane * 8);
            const bf16x8 b1 = *(const bf16x8*)(wf + (1 * 8 + ct * 2 + 1) * 512 + lane * 8);
            f32x4 acc = {0.f, 0.f, 0.f, 0.f};
            acc = __builtin_amdgcn_mfma_f32_16x16x32_bf16(a2[0], b0, acc, 0, 0, 0);
            acc = __builtin_amdgcn_mfma_f32_16x16x32_bf16(a2[1], b1, acc, 0, 0, 0);
            const float bv = bb[ct * 16 + l15];
#pragma unroll
            for (int r = 0; r < 4; ++r) {
                float h = acc[r] + bv;
                h = h > 0.f ? h : 0.f;
                hs[quad * 4 + r][ct * 16 + l15] = (bf16_t)h;
            }
        }
    }

    __syncthreads();   // final h complete

    if (POOL) {
        // segmented mean-pool numerator: each wave scans its own 8 rows
        int cur = -1;
        float acc = 0.f;
        for (int r = 0; r < 8; ++r) {
            const int row = r0w + r;
            const int g = batch[row];           // wave-uniform
            const float v = (float)hs[half * 8 + r][lane];
            if (g != cur) {
                if (cur >= 0) unsafeAtomicAdd(gsum + cur * 64 + lane, acc);
                acc = 0.f;
                cur = g;
            }
            acc += v;
        }
        if (cur >= 0) unsafeAtomicAdd(gsum + cur * 64 + lane, acc);
    } else {
        // wave stores its 8 rows: one bf16x8 per lane
        const int row16 = half * 8 + (lane >> 3);
        const int colg  = (lane & 7) * 8;
        const bf16x8 v = *(const bf16x8*)&hs[row16][colg];
        *(bf16x8*)(xout + (rb + row16) * 64 + colg) = v;
    }
}

// out[g][c] = (gsum[g]/max(cnt,1)) . wc[:,c] + bc[c]; cnt via binary search
__global__ void cls_kernel(const float* __restrict__ gsum,
                           const int* __restrict__ batch,
                           const float* __restrict__ wc, const float* __restrict__ bc,
                           float* __restrict__ out) {
    const int g = blockIdx.x;
    const int c = threadIdx.x;
    if (c >= N_CLS) return;
    int lo = 0, hi = N_NODES;
    while (lo < hi) { const int m = (lo + hi) >> 1; if (batch[m] < g) lo = m + 1; else hi = m; }
    const int lb = lo;
    lo = 0; hi = N_NODES;
    while (lo < hi) { const int m = (lo + hi) >> 1; if (batch[m] <= g) lo = m + 1; else hi = m; }
    const int cnt = lo - lb;
    const float inv = 1.f / (float)(cnt > 1 ? cnt : 1);
    float acc = bc[c];
    for (int k = 0; k < 64; ++k)
        acc += gsum[g * 64 + k] * inv * wc[k * N_CLS + c];
    out[g * N_CLS + c] = acc;
}

// ---------------------------------------------------------------------------
extern "C" void kernel_launch(void* const* d_in, const int* in_sizes, int n_in,
                              void* d_out, int out_size, void* d_ws, size_t ws_size,
                              hipStream_t stream) {
    const float* x   = (const float*)d_in[0];
    const float* w1a = (const float*)d_in[1];
    const float* b1a = (const float*)d_in[2];
    const float* w1b = (const float*)d_in[3];
    const float* b1b = (const float*)d_in[4];
    const float* w2a = (const float*)d_in[5];
    const float* b2a = (const float*)d_in[6];
    const float* w2b = (const float*)d_in[7];
    const float* b2b = (const float*)d_in[8];
    const float* w3a = (const float*)d_in[9];
    const float* b3a = (const float*)d_in[10];
    const float* w3b = (const float*)d_in[11];
    const float* b3b = (const float*)d_in[12];
    const float* wc  = (const float*)d_in[13];
    const float* bc  = (const float*)d_in[14];
    const int*   ei    = (const int*)d_in[15];
    const int*   batch = (const int*)d_in[16];
    float* out = (float*)d_out;

    // workspace layout (~50.1 MB, 16B-aligned; feature buffers have +128B zero pad row)
    char*   ws     = (char*)d_ws;
    int*    bcnt   = (int*)ws;                      // 391 ints (pad 1568)
    int*    offset = (int*)(ws + 3136);             // N+1 ints (pad 400016)
    int*    csr    = (int*)(ws + 403152);           // E ints = 4,800,000
    int*    bpair  = (int*)(ws + 5203152);          // 391*4096*4 = 6,406,144
    bf16_t* xbf    = (bf16_t*)(ws + 11609296);      // 12,800,128 (incl pad row)
    bf16_t* h      = (bf16_t*)(ws + 24409424);      // 12,800,128
    bf16_t* xA     = (bf16_t*)(ws + 37209552);      // 12,800,128
    float*  gsum   = (float*)(ws + 50009680);       // 32,768
    bf16_t* wfragG = (bf16_t*)(ws + 50042448);      // 3*2*8*512 bf16 = 49,152 B

    const int e4grid = (N_EDGES / 4 + 255) / 256;   // 1172
    const int tiles  = N_NODES / 16;                // 6250 (exact)

    // x -> bf16 (+ zero bcnt/gsum/pad rows, pack weight frags)
    tobf_kernel<<<(N_NODES * 64) / (256 * 8), 256, 0, stream>>>(
        x, xbf, bcnt, gsum, w1a, w1b, w2a, w2b, w3a, w3b, wfragG, h, xA);

    // CSR build (once, reused 3x)
    binA_kernel<<<e4grid, 256, 0, stream>>>(ei, bcnt, bpair);
    sortfill_kernel<<<NBUCK, 256, 0, stream>>>(bpair, bcnt, offset, csr);

    // fused gather+MLP layers (ping-pong buffers: xbf -> xA -> h -> pool)
    gmlp_kernel<0><<<tiles, 128, 0, stream>>>(xbf, offset, csr, wfragG,         b1a, b1b, xA, nullptr, nullptr);
    gmlp_kernel<0><<<tiles, 128, 0, stream>>>(xA,  offset, csr, wfragG + 8192,  b2a, b2b, h,  nullptr, nullptr);
    gmlp_kernel<1><<<tiles, 128, 0, stream>>>(h,   offset, csr, wfragG + 16384, b3a, b3b, nullptr, batch, gsum);

    // classify
    cls_kernel<<<N_GRAPH, 64, 0, stream>>>(gsum, batch, wc, bc, out);
}

// Round 6
// 282.242 us; speedup vs baseline: 1.2896x; 1.0194x over previous
//
#include <hip/hip_runtime.h>
#include <hip/hip_bf16.h>

// GIN: 3x fused [CSR gather-sum + MLP(64->64->64) + relu] + mean-pool(128) + linear(64->10)
// gmlp v6: 128-thread blocks (2 waves = one 16-row MFMA tile), 6250 blocks.
//   Gather: 2 neighbor rows per load instruction (lane>>5 selects neighbor,
//   (lane&31)*2 the column pair; 4B/lane). G8P group = 16 neighbors; mean degree
//   12 -> 1 group/row. Doubles bytes-in-flight at the ~16-instruction scheduled
//   depth that bounded r2-r5 (BW tracked occupancy*0.043 TB/s). Zero-pad row
//   absorbs tails; per-row combine = shfl_xor(32).
//   Weights pre-packed bf16 in global (broadcast 16B loads); LDS 4.6KB/block.
// CSR: 391-bucket binning + per-bucket counting sort w/ inline prefix.
// tobf zeroes bcnt/gsum/pad-rows + packs 3 layers' weight frags. 7 dispatches.

#define N_NODES 100000
#define N_EDGES 1200000
#define N_GRAPH 128
#define N_CLS   10
#define NBUCK   391        // dst >> 8
#define BCAP    4096       // per-bucket capacity (mean 3070, +18 sigma)
#define BSH     12         // log2(BCAP)

typedef __bf16 bf16_t;
typedef __bf16 bf16x2 __attribute__((ext_vector_type(2)));
typedef __bf16 bf16x8 __attribute__((ext_vector_type(8)));
typedef float  f32x4  __attribute__((ext_vector_type(4)));
typedef unsigned int uint32;

__device__ __forceinline__ float bflo(uint32 u) {
    return __uint_as_float(u << 16);
}
__device__ __forceinline__ float bfhi(uint32 u) {
    return __uint_as_float(u & 0xffff0000u);
}

// ---------------- x -> bf16 (+ zero bcnt/gsum/pads, + pack weight frags) ----------------
__global__ void tobf_kernel(const float* __restrict__ x, bf16_t* __restrict__ xb,
                            int* __restrict__ bcnt, float* __restrict__ gsum,
                            const float* __restrict__ w1a, const float* __restrict__ w1b,
                            const float* __restrict__ w2a, const float* __restrict__ w2b,
                            const float* __restrict__ w3a, const float* __restrict__ w3b,
                            bf16_t* __restrict__ wfragG,
                            bf16_t* __restrict__ hPad, bf16_t* __restrict__ xAPad) {
    const int tid = threadIdx.x;
    if (blockIdx.x == 0) {
        for (int i = tid; i < NBUCK; i += 256) bcnt[i] = 0;
    } else if (blockIdx.x == 1) {
        f32x4* g4 = (f32x4*)gsum;
        for (int i = tid; i < N_GRAPH * 16; i += 256)   // 8192 f32
            g4[i] = (f32x4){0.f, 0.f, 0.f, 0.f};
        if (tid < 64) {                                  // zero-pad rows (idx N_NODES)
            xb[N_NODES * 64 + tid]    = (bf16_t)0.f;
            hPad[N_NODES * 64 + tid]  = (bf16_t)0.f;
            xAPad[N_NODES * 64 + tid] = (bf16_t)0.f;
        }
    } else if (blockIdx.x <= 4) {
        // pack layer L's weight fragments: wfragG[((L*2+m)*8+fi)*512 + lane*8 + j]
        const int L = blockIdx.x - 2;
        const float* wA = L == 0 ? w1a : (L == 1 ? w2a : w3a);
        const float* wB = L == 0 ? w1b : (L == 1 ? w2b : w3b);
        const int k  = tid >> 2;
        const int n0 = (tid & 3) << 4;
        const int ks = k >> 5, qd = (k >> 3) & 3, jj = k & 7;
        const int fi = ((n0 >> 4) << 1) + ks;
#pragma unroll
        for (int m = 0; m < 2; ++m) {
            const float* w = m ? wB : wA;
            const f32x4 v0 = *(const f32x4*)(w + k * 64 + n0);
            const f32x4 v1 = *(const f32x4*)(w + k * 64 + n0 + 4);
            const f32x4 v2 = *(const f32x4*)(w + k * 64 + n0 + 8);
            const f32x4 v3 = *(const f32x4*)(w + k * 64 + n0 + 12);
            bf16_t* dst = wfragG + ((L * 2 + m) * 8 + fi) * 512 + jj;
#pragma unroll
            for (int l = 0; l < 4; ++l) {
                dst[(qd * 16 + l) * 8]      = (bf16_t)v0[l];
                dst[(qd * 16 + 4 + l) * 8]  = (bf16_t)v1[l];
                dst[(qd * 16 + 8 + l) * 8]  = (bf16_t)v2[l];
                dst[(qd * 16 + 12 + l) * 8] = (bf16_t)v3[l];
            }
        }
    }
    const int i = (blockIdx.x * 256 + tid) * 8;
    const f32x4 a = *(const f32x4*)(x + i);
    const f32x4 b = *(const f32x4*)(x + i + 4);
    bf16x8 o;
#pragma unroll
    for (int j = 0; j < 4; ++j) { o[j] = (bf16_t)a[j]; o[4 + j] = (bf16_t)b[j]; }
    *(bf16x8*)(xb + i) = o;
}

// ---------------- CSR build ----------------
__global__ void binA_kernel(const int* __restrict__ ei,
                            int* __restrict__ bcnt,
                            int* __restrict__ bpair) {
    __shared__ int lcnt[NBUCK];
    __shared__ int lbase[NBUCK];
    const int t = threadIdx.x;
    for (int b = t; b < NBUCK; b += 256) lcnt[b] = 0;
    __syncthreads();
    const int e0 = (blockIdx.x * 256 + t) * 4;
    int4 s4, d4; int b[4], r[4];
    const bool valid = e0 < N_EDGES;               // N_EDGES % 4 == 0
    if (valid) {
        s4 = *(const int4*)(ei + e0);
        d4 = *(const int4*)(ei + N_EDGES + e0);
        b[0] = d4.x >> 8; b[1] = d4.y >> 8; b[2] = d4.z >> 8; b[3] = d4.w >> 8;
        r[0] = atomicAdd(&lcnt[b[0]], 1);
        r[1] = atomicAdd(&lcnt[b[1]], 1);
        r[2] = atomicAdd(&lcnt[b[2]], 1);
        r[3] = atomicAdd(&lcnt[b[3]], 1);
    }
    __syncthreads();
    for (int bb = t; bb < NBUCK; bb += 256) {
        const int c = lcnt[bb];
        lbase[bb] = c ? atomicAdd(&bcnt[bb], c) : 0;
    }
    __syncthreads();
    if (valid) {
        const int ss[4] = {s4.x, s4.y, s4.z, s4.w};
        const int dd[4] = {d4.x, d4.y, d4.z, d4.w};
#pragma unroll
        for (int j = 0; j < 4; ++j) {
            const int slot = lbase[b[j]] + r[j];
            if (slot < BCAP)
                bpair[(b[j] << BSH) + slot] = (ss[j] << 8) | (dd[j] & 255);
        }
    }
}

// one WG per bucket: inline prefix over min(bcnt,BCAP) + LDS counting sort
__global__ void sortfill_kernel(const int* __restrict__ bpair,
                                const int* __restrict__ bcnt,
                                int* __restrict__ offset, int* __restrict__ csr) {
    __shared__ int red[256];
    __shared__ int hist[256];
    __shared__ int l[256];
    __shared__ int cursor[256];
    const int b = blockIdx.x;
    const int t = threadIdx.x;
    const int base = b << BSH;

    // prefix: cbase = sum_{i<b} min(bcnt[i],BCAP); cnt = min(bcnt[b],BCAP)
    int part = 0;
    for (int i = t; i < b; i += 256) {
        int c = bcnt[i];
        part += (c < BCAP ? c : BCAP);
    }
    red[t] = part;
    __syncthreads();
    for (int d = 128; d > 0; d >>= 1) {
        if (t < d) red[t] += red[t + d];
        __syncthreads();
    }
    const int cbase = red[0];
    int cnt = bcnt[b];
    cnt = cnt < BCAP ? cnt : BCAP;
    if (b == NBUCK - 1 && t == 0) offset[N_NODES] = cbase + cnt;
    __syncthreads();

    hist[t] = 0;
    __syncthreads();
    for (int i = t; i < cnt; i += 256)
        atomicAdd(&hist[bpair[base + i] & 255], 1);
    __syncthreads();

    const int v = hist[t];
    l[t] = v;
    __syncthreads();
    for (int d = 1; d < 256; d <<= 1) {
        int u = l[t];
        if (t >= d) u += l[t - d];
        __syncthreads();
        l[t] = u;
        __syncthreads();
    }
    const int gpos = cbase + l[t] - v;              // exclusive
    const int node = (b << 8) + t;
    if (node < N_NODES) offset[node] = gpos;
    cursor[t] = gpos;
    __syncthreads();

    for (int i = t; i < cnt; i += 256) {
        const int p = bpair[base + i];
        const int pos = atomicAdd(&cursor[p & 255], 1);
        csr[pos] = p >> 8;
    }
}

// ---------------------------------------------------------------------------
// Pair-gather group: 8 load instructions cover 16 neighbors (2 rows each,
// lane>>5 selects which; 4B/lane = 2 bf16 columns). Pad index N_NODES ->
// zero row (L1-hot).
// ---------------------------------------------------------------------------
#define G8P(S, J, AX, AY)                                                      \
    {                                                                          \
        const int t0 = __shfl(S, (J) + 0  + idx), t1 = __shfl(S, (J) + 2  + idx);\
        const int t2 = __shfl(S, (J) + 4  + idx), t3 = __shfl(S, (J) + 6  + idx);\
        const int t4 = __shfl(S, (J) + 8  + idx), t5 = __shfl(S, (J) + 10 + idx);\
        const int t6 = __shfl(S, (J) + 12 + idx), t7 = __shfl(S, (J) + 14 + idx);\
        const uint32 u0 = *(const uint32*)(x + t0 * 64 + c2);                  \
        const uint32 u1 = *(const uint32*)(x + t1 * 64 + c2);                  \
        const uint32 u2 = *(const uint32*)(x + t2 * 64 + c2);                  \
        const uint32 u3 = *(const uint32*)(x + t3 * 64 + c2);                  \
        const uint32 u4 = *(const uint32*)(x + t4 * 64 + c2);                  \
        const uint32 u5 = *(const uint32*)(x + t5 * 64 + c2);                  \
        const uint32 u6 = *(const uint32*)(x + t6 * 64 + c2);                  \
        const uint32 u7 = *(const uint32*)(x + t7 * 64 + c2);                  \
        AX += ((bflo(u0) + bflo(u1)) + (bflo(u2) + bflo(u3)))                  \
            + ((bflo(u4) + bflo(u5)) + (bflo(u6) + bflo(u7)));                 \
        AY += ((bfhi(u0) + bfhi(u1)) + (bfhi(u2) + bfhi(u3)))                  \
            + ((bfhi(u4) + bfhi(u5)) + (bfhi(u6) + bfhi(u7)));                 \
    }

// one dual-stream row pair: rows r0w+I (A) and r0w+I+4 (B)
#define ROWPAIR(I, SA, CA, DA, OA, SB, CB, DB, OB)                             \
    {                                                                          \
        const uint32 suA = *(const uint32*)(x + (r0w + I) * 64 + c2);          \
        const uint32 suB = *(const uint32*)(x + (r0w + I + 4) * 64 + c2);      \
        float axA = idx ? 0.f : bflo(suA), ayA = idx ? 0.f : bfhi(suA);        \
        float axB = idx ? 0.f : bflo(suB), ayB = idx ? 0.f : bfhi(suB);        \
        const int cmax = (CA) > (CB) ? (CA) : (CB);                            \
        for (int j = 0; j < cmax; j += 16) {                                   \
            if (j < (CA)) { G8P(SA, j, axA, ayA) }                             \
            if (j < (CB)) { G8P(SB, j, axB, ayB) }                             \
        }                                                                      \
        if ((DA) > 64 || (DB) > 64) {       /* rare long rows */               \
            for (int base = 64; base < (DA) || base < (DB); base += 64) {      \
                const int ra = (DA) - base, rb2 = (DB) - base;                 \
                const int ca2 = ra <= 0 ? 0 : (ra < 64 ? ra : 64);             \
                const int cb2 = rb2 <= 0 ? 0 : (rb2 < 64 ? rb2 : 64);          \
                int sA2 = N_NODES, sB2 = N_NODES;                              \
                if (f < ca2) sA2 = csr[(OA) + base + f];                       \
                if (f < cb2) sB2 = csr[(OB) + base + f];                       \
                const int cm2 = ca2 > cb2 ? ca2 : cb2;                         \
                for (int j = 0; j < cm2; j += 16) {                            \
                    if (j < ca2) { G8P(sA2, j, axA, ayA) }                     \
                    if (j < cb2) { G8P(sB2, j, axB, ayB) }                     \
                }                                                              \
            }                                                                  \
        }                                                                      \
        axA += __shfl_xor(axA, 32); ayA += __shfl_xor(ayA, 32);                \
        axB += __shfl_xor(axB, 32); ayB += __shfl_xor(ayB, 32);                \
        if (idx == 0) {                                                        \
            bf16x2 wA2 = {(bf16_t)axA, (bf16_t)ayA};                           \
            bf16x2 wB2 = {(bf16_t)axB, (bf16_t)ayB};                           \
            *(bf16x2*)(&hs[half * 8 + I][c2])     = wA2;                       \
            *(bf16x2*)(&hs[half * 8 + I + 4][c2]) = wB2;                       \
        }                                                                      \
    }

// ---------------------------------------------------------------------------
// Fused gather + MLP, one 16-row tile per 128-thread block (2 waves).
// Wave half gathers 8 rows (4 dual-stream pairs, csr indices all preloaded);
// each wave computes 2 of 4 col-tiles of the 16x64 MLP. Weight B-fragments and
// biases from global (wf: pre-packed bf16; broadcast loads).
// POOL=1 (layer 3): each wave emits segmented mean-pool numerator atomics.
// ---------------------------------------------------------------------------
template <int POOL>
__global__ void gmlp_kernel(const bf16_t* __restrict__ x,
                            const int* __restrict__ offset,
                            const int* __restrict__ csr,
                            const bf16_t* __restrict__ wf,   // [m*8+fi][lane][8] bf16
                            const float* __restrict__ ba, const float* __restrict__ bb,
                            bf16_t* __restrict__ xout,
                            const int* __restrict__ batch,
                            float* __restrict__ gsum) {
    __shared__ __align__(16) bf16_t hs[16][72];   // agg rows, then h2 (final)
    __shared__ __align__(16) bf16_t h2[16][72];   // h1 (GEMM1 out)

    const int tid  = threadIdx.x;
    const int half = tid >> 6;          // 0..1
    const int lane = tid & 63;
    const int l15  = lane & 15;
    const int quad = lane >> 4;
    const int idx  = lane >> 5;         // which of 2 neighbors per load
    const int c2   = (lane & 31) * 2;   // column pair

    const int rb  = blockIdx.x * 16;    // tile's first row (N_NODES % 16 == 0)
    const int r0w = rb + half * 8;      // this wave's first row
    const int f   = lane;

    // prefetch the 9 offsets this wave needs, broadcast via shfl
    int offv = 0;
    if (lane < 9) offv = offset[r0w + lane];
    const int o0 = __shfl(offv, 0), o1 = __shfl(offv, 1), o2 = __shfl(offv, 2);
    const int o3 = __shfl(offv, 3), o4 = __shfl(offv, 4), o5 = __shfl(offv, 5);
    const int o6 = __shfl(offv, 6), o7 = __shfl(offv, 7), o8 = __shfl(offv, 8);
    const int d0 = o1 - o0, d1 = o2 - o1, d2 = o3 - o2, d3 = o4 - o3;
    const int d4 = o5 - o4, d5 = o6 - o5, d6 = o7 - o6, d7 = o8 - o7;
    const int c0 = d0 < 64 ? d0 : 64, c1 = d1 < 64 ? d1 : 64;
    const int c2_ = d2 < 64 ? d2 : 64, c3 = d3 < 64 ? d3 : 64;
    const int c4 = d4 < 64 ? d4 : 64, c5 = d5 < 64 ? d5 : 64;
    const int c6 = d6 < 64 ? d6 : 64, c7 = d7 < 64 ? d7 : 64;

    // preload all 8 rows' first-chunk csr index vectors (8 coalesced loads in flight)
    int s0 = N_NODES, s1 = N_NODES, s2 = N_NODES, s3 = N_NODES;
    int s4 = N_NODES, s5 = N_NODES, s6 = N_NODES, s7 = N_NODES;
    if (f < c0)  s0 = csr[o0 + f];
    if (f < c1)  s1 = csr[o1 + f];
    if (f < c2_) s2 = csr[o2 + f];
    if (f < c3)  s3 = csr[o3 + f];
    if (f < c4)  s4 = csr[o4 + f];
    if (f < c5)  s5 = csr[o5 + f];
    if (f < c6)  s6 = csr[o6 + f];
    if (f < c7)  s7 = csr[o7 + f];

    // ---- gather 8 rows into hs (pairs (i, i+4); 2 neighbor rows per load) ----
    ROWPAIR(0, s0, c0, d0, o0, s4, c4, d4, o4)
    ROWPAIR(1, s1, c1, d1, o1, s5, c5, d5, o5)
    ROWPAIR(2, s2, c2_, d2, o2, s6, c6, d6, o6)
    ROWPAIR(3, s3, c3, d3, o3, s7, c7, d7, o7)

    __syncthreads();   // gather done

    // ---- GEMM1: read hs, write relu -> h2; this wave owns ct = half*2 + {0,1}
    {
        bf16x8 af[2];
#pragma unroll
        for (int ks = 0; ks < 2; ++ks)
            af[ks] = *(const bf16x8*)(&hs[l15][ks * 32 + quad * 8]);
#pragma unroll
        for (int c = 0; c < 2; ++c) {
            const int ct = half * 2 + c;
            const bf16x8 b0 = *(const bf16x8*)(wf + (0 * 8 + ct * 2 + 0) * 512 + lane * 8);
            const bf16x8 b1 = *(const bf16x8*)(wf + (0 * 8 + ct * 2 + 1) * 512 + lane * 8);
            f32x4 acc = {0.f, 0.f, 0.f, 0.f};
            acc = __builtin_amdgcn_mfma_f32_16x16x32_bf16(af[0], b0, acc, 0, 0, 0);
            acc = __builtin_amdgcn_mfma_f32_16x16x32_bf16(af[1], b1, acc, 0, 0, 0);
            const float bv = ba[ct * 16 + l15];
#pragma unroll
            for (int r = 0; r < 4; ++r) {
                float h = acc[r] + bv;
                h = h > 0.f ? h : 0.f;
                h2[quad * 4 + r][ct * 16 + l15] = (bf16_t)h;
            }
        }
    }

    __syncthreads();   // h1 complete

    // ---- GEMM2: read h2, write relu -> hs
    {
        bf16x8 a2[2];
#pragma unroll
        for (int ks = 0; ks < 2; ++ks)
            a2[ks] = *(const bf16x8*)(&h2[l15][ks * 32 + quad * 8]);
#pragma unroll
        for (int c = 0; c < 2; ++c) {
            const int ct = half * 2 + c;
            const bf16x8 b0 = *(const bf16x8*)(wf + (1 * 8 + ct * 2 + 0) * 512 + lane * 8);
            const bf16x8 b1 = *(const bf16x8*)(wf + (1 * 8 + ct * 2 + 1) * 512 + lane * 8);
            f32x4 acc = {0.f, 0.f, 0.f, 0.f};
            acc = __builtin_amdgcn_mfma_f32_16x16x32_bf16(a2[0], b0, acc, 0, 0, 0);
            acc = __builtin_amdgcn_mfma_f32_16x16x32_bf16(a2[1], b1, acc, 0, 0, 0);
            const float bv = bb[ct * 16 + l15];
#pragma unroll
            for (int r = 0; r < 4; ++r) {
                float h = acc[r] + bv;
                h = h > 0.f ? h : 0.f;
                hs[quad * 4 + r][ct * 16 + l15] = (bf16_t)h;
            }
        }
    }

    __syncthreads();   // final h complete

    if (POOL) {
        // segmented mean-pool numerator: each wave scans its own 8 rows
        int cur = -1;
        float acc = 0.f;
        for (int r = 0; r < 8; ++r) {
            const int row = r0w + r;
            const int g = batch[row];           // wave-uniform
            const float v = (float)hs[half * 8 + r][lane];
            if (g != cur) {
                if (cur >= 0) unsafeAtomicAdd(gsum + cur * 64 + lane, acc);
                acc = 0.f;
                cur = g;
            }
            acc += v;
        }
        if (cur >= 0) unsafeAtomicAdd(gsum + cur * 64 + lane, acc);
    } else {
        // wave stores its 8 rows: one bf16x8 per lane
        const int row16 = half * 8 + (lane >> 3);
        const int colg  = (lane & 7) * 8;
        const bf16x8 v = *(const bf16x8*)&hs[row16][colg];
        *(bf16x8*)(xout + (rb + row16) * 64 + colg) = v;
    }
}

// out[g][c] = (gsum[g]/max(cnt,1)) . wc[:,c] + bc[c]; cnt via binary search
__global__ void cls_kernel(const float* __restrict__ gsum,
                           const int* __restrict__ batch,
                           const float* __restrict__ wc, const float* __restrict__ bc,
                           float* __restrict__ out) {
    const int g = blockIdx.x;
    const int c = threadIdx.x;
    if (c >= N_CLS) return;
    int lo = 0, hi = N_NODES;
    while (lo < hi) { const int m = (lo + hi) >> 1; if (batch[m] < g) lo = m + 1; else hi = m; }
    const int lb = lo;
    lo = 0; hi = N_NODES;
    while (lo < hi) { const int m = (lo + hi) >> 1; if (batch[m] <= g) lo = m + 1; else hi = m; }
    const int cnt = lo - lb;
    const float inv = 1.f / (float)(cnt > 1 ? cnt : 1);
    float acc = bc[c];
    for (int k = 0; k < 64; ++k)
        acc += gsum[g * 64 + k] * inv * wc[k * N_CLS + c];
    out[g * N_CLS + c] = acc;
}

// ---------------------------------------------------------------------------
extern "C" void kernel_launch(void* const* d_in, const int* in_sizes, int n_in,
                              void* d_out, int out_size, void* d_ws, size_t ws_size,
                              hipStream_t stream) {
    const float* x   = (const float*)d_in[0];
    const float* w1a = (const float*)d_in[1];
    const float* b1a = (const float*)d_in[2];
    const float* w1b = (const float*)d_in[3];
    const float* b1b = (const float*)d_in[4];
    const float* w2a = (const float*)d_in[5];
    const float* b2a = (const float*)d_in[6];
    const float* w2b = (const float*)d_in[7];
    const float* b2b = (const float*)d_in[8];
    const float* w3a = (const float*)d_in[9];
    const float* b3a = (const float*)d_in[10];
    const float* w3b = (const float*)d_in[11];
    const float* b3b = (const float*)d_in[12];
    const float* wc  = (const float*)d_in[13];
    const float* bc  = (const float*)d_in[14];
    const int*   ei    = (const int*)d_in[15];
    const int*   batch = (const int*)d_in[16];
    float* out = (float*)d_out;

    // workspace layout (~50.1 MB, 16B-aligned; feature buffers have +128B zero pad row)
    char*   ws     = (char*)d_ws;
    int*    bcnt   = (int*)ws;                      // 391 ints (pad 1568)
    int*    offset = (int*)(ws + 3136);             // N+1 ints (pad 400016)
    int*    csr    = (int*)(ws + 403152);           // E ints = 4,800,000
    int*    bpair  = (int*)(ws + 5203152);          // 391*4096*4 = 6,406,144
    bf16_t* xbf    = (bf16_t*)(ws + 11609296);      // 12,800,128 (incl pad row)
    bf16_t* h      = (bf16_t*)(ws + 24409424);      // 12,800,128
    bf16_t* xA     = (bf16_t*)(ws + 37209552);      // 12,800,128
    float*  gsum   = (float*)(ws + 50009680);       // 32,768
    bf16_t* wfragG = (bf16_t*)(ws + 50042448);      // 3*2*8*512 bf16 = 49,152 B

    const int e4grid = (N_EDGES / 4 + 255) / 256;   // 1172
    const int tiles  = N_NODES / 16;                // 6250 (exact)

    // x -> bf16 (+ zero bcnt/gsum/pad rows, pack weight frags)
    tobf_kernel<<<(N_NODES * 64) / (256 * 8), 256, 0, stream>>>(
        x, xbf, bcnt, gsum, w1a, w1b, w2a, w2b, w3a, w3b, wfragG, h, xA);

    // CSR build (once, reused 3x)
    binA_kernel<<<e4grid, 256, 0, stream>>>(ei, bcnt, bpair);
    sortfill_kernel<<<NBUCK, 256, 0, stream>>>(bpair, bcnt, offset, csr);

    // fused gather+MLP layers (ping-pong buffers: xbf -> xA -> h -> pool)
    gmlp_kernel<0><<<tiles, 128, 0, stream>>>(xbf, offset, csr, wfragG,         b1a, b1b, xA, nullptr, nullptr);
    gmlp_kernel<0><<<tiles, 128, 0, stream>>>(xA,  offset, csr, wfragG + 8192,  b2a, b2b, h,  nullptr, nullptr);
    gmlp_kernel<1><<<tiles, 128, 0, stream>>>(h,   offset, csr, wfragG + 16384, b3a, b3b, nullptr, batch, gsum);

    // classify
    cls_kernel<<<N_GRAPH, 64, 0, stream>>>(gsum, batch, wc, bc, out);
}